// Round 11
// baseline (356.013 us; speedup 1.0000x reference)
//
#include <hip/hip_runtime.h>
#include <math.h>

#define N_NODES 100000
#define N_EDGES 1600000
#define F 128

// CSR radix: buckets of 512 destination nodes, fixed-capacity segments
#define BSH 9
#define NBUCK 196          // ceil(100000 / 512)
#define BCAP 10240         // per-bucket capacity (mean 8163, +22 sigma)
#define PB_EDGES 4096      // edges per k_part block

typedef unsigned int u32;
typedef unsigned short u16;
typedef __attribute__((ext_vector_type(8))) short short8;
typedef __attribute__((ext_vector_type(4))) float floatx4;

// ---------------- helpers ----------------

__device__ __forceinline__ u32 key_of(float s) {
    u32 u = __float_as_uint(s);
    return (u & 0x80000000u) ? ~u : (u | 0x80000000u);   // larger float -> larger key
}

__device__ __forceinline__ float wave_reduce(float v) {
    #pragma unroll
    for (int off = 32; off > 0; off >>= 1) v += __shfl_down(v, off, 64);
    return v;
}

__device__ __forceinline__ u16 f2bf(float f) {   // round-to-nearest-even
    u32 u = __float_as_uint(f);
    u += 0x7fffu + ((u >> 16) & 1u);
    return (u16)(u >> 16);
}

__device__ __forceinline__ float bflo(u32 b) { return __uint_as_float(b << 16); }
__device__ __forceinline__ float bfhi(u32 b) { return __uint_as_float(b & 0xffff0000u); }

// ---------------- 1. scores[i] = x[i] . p  (+ fused 16-bit key histogram) ----------

__global__ void k_scores(const float* __restrict__ x, const float* __restrict__ p,
                         float* __restrict__ scores, u32* __restrict__ hist16) {
    int node = blockIdx.x * 4 + (threadIdx.x >> 6);
    int lane = threadIdx.x & 63;
    if (node >= N_NODES) return;
    float2 xv = *(const float2*)&x[(size_t)node * F + lane * 2];
    float2 pv = *(const float2*)&p[lane * 2];
    float d = xv.x * pv.x + xv.y * pv.y;
    d = wave_reduce(d);
    if (lane == 0) {
        scores[node] = d;
        atomicAdd(&hist16[key_of(d) >> 16], 1u);
    }
}

// ---------------- 2. fused top-128 select (single block):
// threshold scan -> collect -> exact rank sort (jax tie semantics) ----------------

__global__ __launch_bounds__(1024) void k_topsel(const float* __restrict__ scores,
                                                 const float* __restrict__ p,
                                                 const u32* __restrict__ hist16,
                                                 u32* __restrict__ top_idx,
                                                 float* __restrict__ gate) {
    __shared__ u32 a[1024];
    __shared__ u32 ci[2048];
    __shared__ float csc[2048];
    __shared__ u32 sh_T, sh_n;
    __shared__ float s_inv;
    int t = threadIdx.x;
    if (t == 0) sh_n = 0u;
    if (t < 64) {
        float2 pv = *(const float2*)&p[t * 2];
        float d = pv.x * pv.x + pv.y * pv.y;
        d = wave_reduce(d);
        if (t == 0) s_inv = rsqrtf(d);
    }
    // --- threshold bucket from 16-bit histogram (suffix scan over 1024 chunks)
    const uint4* h4 = (const uint4*)hist16;
    u32 local = 0;
    #pragma unroll
    for (int i = 0; i < 16; i++) {
        uint4 v = h4[t * 16 + i];
        local += v.x + v.y + v.z + v.w;
    }
    a[t] = local;
    __syncthreads();
    for (int off = 1; off < 1024; off <<= 1) {
        u32 add = (t + off < 1024) ? a[t + off] : 0u;
        __syncthreads();
        a[t] += add;
        __syncthreads();
    }
    u32 S_above = (t == 1023) ? 0u : a[t + 1];
    if (S_above < 128u && a[t] >= 128u) {     // threshold bucket in my 64-bin chunk
        u32 cum = S_above;
        for (int v = t * 64 + 63; v >= t * 64; v--) {
            cum += hist16[v];
            if (cum >= 128u) { sh_T = ((u32)v) << 16; break; }
        }
    }
    __syncthreads();
    // --- collect candidates (keys >= threshold bucket base)
    u32 T = sh_T;
    for (int i = t; i < N_NODES; i += 1024) {
        float s = scores[i];
        if (key_of(s) >= T) {
            u32 pos = atomicAdd(&sh_n, 1u);
            if (pos < 2048u) { ci[pos] = (u32)i; csc[pos] = s; }
        }
    }
    __syncthreads();
    // --- exact rank sort: value desc, index asc on ties
    u32 nc = sh_n; if (nc > 2048u) nc = 2048u;
    for (u32 i = t; i < nc; i += 1024) {
        u32 myk = key_of(csc[i]);
        u32 myi = ci[i];
        int rank = 0;
        for (u32 j = 0; j < nc; j++) {
            u32 ok = key_of(csc[j]);
            rank += (int)((ok > myk) || (ok == myk && ci[j] < myi));
        }
        if (rank < 128) {
            top_idx[rank] = myi;
            gate[rank] = tanhf(csc[i] * s_inv);
        }
    }
}

// ---------------- 3a. GRU GEMMs: g[128][768] = [x_tilde | W] . [w_ih | w_hh]^T -----

__global__ __launch_bounds__(256) void k_ggemm(const float* __restrict__ x,
                                               const float* __restrict__ W,
                                               const float* __restrict__ w_ih,
                                               const float* __restrict__ w_hh,
                                               const u32* __restrict__ top_idx,
                                               const float* __restrict__ gate,
                                               float* __restrict__ G) {
    __shared__ float As[32][128];
    __shared__ float Bs[64][131];
    int t = threadIdx.x;
    int k0 = blockIdx.x * 32;
    int by = blockIdx.y;                // 0..11; <6 -> gi (w_ih, x_tilde), else gh
    int j0 = by * 64;
    bool is_gi = (by < 6);
    #pragma unroll
    for (int i = 0; i < 4; i++) {
        int l = t + i * 256;
        int row = l >> 5, c4 = l & 31;
        float4 v;
        if (is_gi) {
            u32 idx = top_idx[k0 + row];
            float gt = gate[k0 + row];
            v = *(const float4*)&x[(size_t)idx * F + c4 * 4];
            v.x *= gt; v.y *= gt; v.z *= gt; v.w *= gt;
        } else {
            v = *(const float4*)&W[(k0 + row) * F + c4 * 4];
        }
        *(float4*)&As[row][c4 * 4] = v;
    }
    const float* mat = is_gi ? w_ih : w_hh;
    int jbase = is_gi ? j0 : (j0 - 384);
    #pragma unroll
    for (int i = 0; i < 8; i++) {
        int l = t + i * 256;
        int row = l >> 5, c4 = l & 31;
        float4 v = *(const float4*)&mat[(jbase + row) * F + c4 * 4];
        Bs[row][c4 * 4 + 0] = v.x; Bs[row][c4 * 4 + 1] = v.y;
        Bs[row][c4 * 4 + 2] = v.z; Bs[row][c4 * 4 + 3] = v.w;
    }
    __syncthreads();
    int ty = t >> 5, tx = t & 31;
    float acc[4][2] = {};
    #pragma unroll 4
    for (int f = 0; f < 128; f++) {
        float b0 = Bs[tx * 2][f], b1 = Bs[tx * 2 + 1][f];
        #pragma unroll
        for (int i = 0; i < 4; i++) {
            float a = As[ty * 4 + i][f];
            acc[i][0] += a * b0;
            acc[i][1] += a * b1;
        }
    }
    #pragma unroll
    for (int i = 0; i < 4; i++) {
        int k = k0 + ty * 4 + i;
        G[(size_t)k * 768 + j0 + tx * 2 + 0] = acc[i][0];
        G[(size_t)k * 768 + j0 + tx * 2 + 1] = acc[i][1];
    }
}

// ---------------- 3b. pointwise GRU gates -> fragment-ordered bf16 B ---------------

__global__ void k_gate(const float* __restrict__ G, const float* __restrict__ W,
                       const float* __restrict__ b_ih, const float* __restrict__ b_hh,
                       u16* __restrict__ Bfrag) {
    int idx = blockIdx.x * blockDim.x + threadIdx.x;   // 16384
    int k = idx >> 7, h = idx & 127;
    const float* gk = &G[(size_t)k * 768];
    float gir = gk[h]       + b_ih[h];
    float giz = gk[128 + h] + b_ih[128 + h];
    float gin = gk[256 + h] + b_ih[256 + h];
    float ghr = gk[384 + h] + b_hh[h];
    float ghz = gk[512 + h] + b_hh[128 + h];
    float ghn = gk[640 + h] + b_hh[256 + h];
    float wv  = W[k * F + h];
    float rg = 1.0f / (1.0f + expf(-(gir + ghr)));
    float z  = 1.0f / (1.0f + expf(-(giz + ghz)));
    float n  = tanhf(gin + rg * ghn);
    float val = (1.0f - z) * n + z * wv;
    int nb = h >> 4, kc = k >> 5, q = (k >> 3) & 3, m = h & 15, jj = k & 7;
    Bfrag[(((nb * 4 + kc) * 64) + q * 16 + m) * 8 + jj] = f2bf(val);
}

// ---------------- 4. CSR build: fixed-capacity radix scatter -----------------------

__global__ void k_part(const int* __restrict__ ei, u32* __restrict__ gcur,
                       u32* __restrict__ pairs) {
    __shared__ u32 lh[NBUCK];     // local histogram, then local cursor
    __shared__ u32 lbase[NBUCK];  // reserved base within bucket segment
    int t = threadIdx.x;
    int e0 = blockIdx.x * PB_EDGES;
    int e1 = e0 + PB_EDGES; if (e1 > N_EDGES) e1 = N_EDGES;
    for (int i = t; i < NBUCK; i += 256) lh[i] = 0u;
    __syncthreads();
    for (int e = e0 + t; e < e1; e += 256)
        atomicAdd(&lh[((u32)ei[N_EDGES + e]) >> BSH], 1u);
    __syncthreads();
    for (int b = t; b < NBUCK; b += 256) {
        u32 c = lh[b];
        lbase[b] = c ? atomicAdd(&gcur[b], c) : 0u;
        lh[b] = 0u;
    }
    __syncthreads();
    for (int e = e0 + t; e < e1; e += 256) {
        u32 d = (u32)ei[N_EDGES + e];
        u32 b = d >> BSH;
        u32 pos = lbase[b] + atomicAdd(&lh[b], 1u);
        pairs[(size_t)b * BCAP + pos] = ((d & 511u) << 17) | (u32)ei[e];
    }
}

__global__ __launch_bounds__(256) void k_csr(const u32* __restrict__ pairs,
                                             const u32* __restrict__ gcur,
                                             u32* __restrict__ offs,
                                             float* __restrict__ dinv,
                                             u32* __restrict__ ebuf) {
    __shared__ u32 h[512];
    __shared__ u32 sc[512];
    __shared__ u32 ps[256];
    int b = blockIdx.x, t = threadIdx.x;
    u32 pv = (t < NBUCK) ? gcur[t] : 0u;
    ps[t] = pv;
    __syncthreads();
    for (int off = 1; off < 256; off <<= 1) {
        u32 add = (t >= off) ? ps[t - off] : 0u;
        __syncthreads();
        ps[t] += add;
        __syncthreads();
    }
    u32 base = ps[b] - gcur[b];
    u32 cnt  = gcur[b];
    const u32* seg = pairs + (size_t)b * BCAP;
    u32 lo = (u32)b << BSH;
    for (int i = t; i < 512; i += 256) h[i] = 0u;
    __syncthreads();
    for (u32 i = t; i < cnt; i += 256)
        atomicAdd(&h[seg[i] >> 17], 1u);
    __syncthreads();
    for (int i = t; i < 512; i += 256) sc[i] = h[i];
    __syncthreads();
    for (int off = 1; off < 512; off <<= 1) {
        int i0 = t, i1 = t + 256;
        u32 v0 = (i0 >= off) ? sc[i0 - off] : 0u;
        u32 v1 = (i1 >= off) ? sc[i1 - off] : 0u;
        __syncthreads();
        sc[i0] += v0; sc[i1] += v1;
        __syncthreads();
    }
    int nn = N_NODES - (int)lo; if (nn > 512) nn = 512;
    for (int i = t; i < nn; i += 256) {
        u32 c = h[i];
        offs[lo + i] = base + (sc[i] - c);
        dinv[lo + i] = rsqrtf((float)c + 1.0f);
    }
    for (int i = t; i < 512; i += 256) sc[i] -= h[i];
    __syncthreads();
    for (u32 i = t; i < cnt; i += 256) {
        u32 pr = seg[i];
        u32 pos = base + atomicAdd(&sc[pr >> 17], 1u);
        ebuf[pos] = pr & 0x1ffffu;
    }
    if (b == 0 && t == 0) offs[N_NODES] = N_EDGES;
}

// ---------------- 5. yw = dinv * (x @ W_new) : bf16 MFMA, direct-global B ---------

__global__ __launch_bounds__(256) void k_gemm(const float* __restrict__ x,
                                              const u16* __restrict__ Bfrag,
                                              const float* __restrict__ dinv,
                                              u16* __restrict__ yw) {
    __shared__ __align__(16) u16 As[8448];    // frag stage (8192) / epilogue 64x132
    int t = threadIdx.x;
    int r0 = blockIdx.x * 64;
    #pragma unroll
    for (int i = 0; i < 8; i++) {
        int l = t + i * 256;              // 2048 float4s
        int row = l >> 5, c4 = l & 31;
        int f0 = c4 * 4;
        float4 v = {0.f, 0.f, 0.f, 0.f};
        if (r0 + row < N_NODES) v = *(const float4*)&x[(size_t)(r0 + row) * F + f0];
        int widx = (((row >> 4) * 4 + (f0 >> 5)) * 64 + ((f0 >> 3) & 3) * 16 + (row & 15)) * 8
                   + (f0 & 7);
        ushort4 s4;
        s4.x = f2bf(v.x); s4.y = f2bf(v.y); s4.z = f2bf(v.z); s4.w = f2bf(v.w);
        *(ushort4*)&As[widx] = s4;
    }
    __syncthreads();

    int wv = t >> 6, lane = t & 63;
    int q = lane >> 4, m = lane & 15;
    floatx4 acc[8] = {};
    #pragma unroll
    for (int kc = 0; kc < 4; kc++) {
        short8 a = *(const short8*)&As[((wv * 4 + kc) * 64 + lane) * 8];
        #pragma unroll
        for (int nb = 0; nb < 8; nb++) {
            short8 bfr = *(const short8*)&Bfrag[((nb * 4 + kc) * 64 + lane) * 8];
            acc[nb] = __builtin_amdgcn_mfma_f32_16x16x32_bf16(a, bfr, acc[nb], 0, 0, 0);
        }
    }
    __syncthreads();   // done reading A-frags; reuse As as epilogue buffer

    float d[4];
    #pragma unroll
    for (int reg = 0; reg < 4; reg++) {
        int gr = r0 + wv * 16 + q * 4 + reg;
        d[reg] = (gr < N_NODES) ? dinv[gr] : 0.f;
    }
    #pragma unroll
    for (int nb = 0; nb < 8; nb++) {
        #pragma unroll
        for (int reg = 0; reg < 4; reg++) {
            int row = wv * 16 + q * 4 + reg;
            As[row * 132 + nb * 16 + m] = f2bf(acc[nb][reg] * d[reg]);
        }
    }
    __syncthreads();
    {
        int row = t >> 2, segi = t & 3;
        int gr = r0 + row;
        if (gr < N_NODES) {
            const uint2* src = (const uint2*)&As[row * 132 + segi * 32];
            uint2* dst = (uint2*)&yw[(size_t)gr * F + segi * 32];
            #pragma unroll
            for (int i = 0; i < 8; i++) dst[i] = src[i];
        }
    }
}

// ---------------- 6. gather-aggregate + fused head (pre-scaled yw rows) -----------
// One wave per node; quarter-wave per edge (uint4 = 8 bf16/lane). Pure adds.
// Launched as TWO half-range dispatches (c0 = node base) for profile visibility.

#define EDGE_GROUP(J) {                                                      \
    u32 r = ebuf[(J) + q];                                                   \
    uint4 bb = *(const uint4*)&yw32[(size_t)r * 64 + sub * 4];               \
    a0 += bflo(bb.x); a1 += bfhi(bb.x);                                      \
    a2 += bflo(bb.y); a3 += bfhi(bb.y);                                      \
    a4 += bflo(bb.z); a5 += bfhi(bb.z);                                      \
    a6 += bflo(bb.w); a7 += bfhi(bb.w); }

__global__ void k_gather(const u32* __restrict__ yw32, const u32* __restrict__ offs,
                         const u32* __restrict__ ebuf, const float* __restrict__ dinv,
                         const float* __restrict__ conv_bias, const float* __restrict__ lin_w,
                         const float* __restrict__ lin_b, float* __restrict__ out,
                         int c0, int cend) {
    int c = c0 + blockIdx.x * 4 + (threadIdx.x >> 6);
    if (c >= cend) return;
    int lane = threadIdx.x & 63;
    int q = lane >> 4, sub = lane & 15;
    u32 jbeg = offs[c], jend = offs[c + 1];
    float a0 = 0.f, a1 = 0.f, a2 = 0.f, a3 = 0.f;
    float a4 = 0.f, a5 = 0.f, a6 = 0.f, a7 = 0.f;
    u32 j = jbeg;
    for (; j + 16 <= jend; j += 16) {   // 16 edges (4 quad-groups) in flight
        EDGE_GROUP(j) EDGE_GROUP(j + 4) EDGE_GROUP(j + 8) EDGE_GROUP(j + 12)
    }
    for (; j + 4 <= jend; j += 4) EDGE_GROUP(j)
    u32 rem = jend - j;
    if (rem) {                           // 1..3 leftover edges
        u32 idx = ((u32)q < rem) ? (j + q) : (jend - 1);
        u32 r = ebuf[idx];
        float mk = ((u32)q < rem) ? 1.f : 0.f;
        uint4 bb = *(const uint4*)&yw32[(size_t)r * 64 + sub * 4];
        a0 += mk * bflo(bb.x); a1 += mk * bfhi(bb.x);
        a2 += mk * bflo(bb.y); a3 += mk * bfhi(bb.y);
        a4 += mk * bflo(bb.z); a5 += mk * bfhi(bb.z);
        a6 += mk * bflo(bb.w); a7 += mk * bfhi(bb.w);
    }
    a0 += __shfl_xor(a0, 16, 64); a0 += __shfl_xor(a0, 32, 64);
    a1 += __shfl_xor(a1, 16, 64); a1 += __shfl_xor(a1, 32, 64);
    a2 += __shfl_xor(a2, 16, 64); a2 += __shfl_xor(a2, 32, 64);
    a3 += __shfl_xor(a3, 16, 64); a3 += __shfl_xor(a3, 32, 64);
    a4 += __shfl_xor(a4, 16, 64); a4 += __shfl_xor(a4, 32, 64);
    a5 += __shfl_xor(a5, 16, 64); a5 += __shfl_xor(a5, 32, 64);
    a6 += __shfl_xor(a6, 16, 64); a6 += __shfl_xor(a6, 32, 64);
    a7 += __shfl_xor(a7, 16, 64); a7 += __shfl_xor(a7, 32, 64);
    float dc = dinv[c];
    uint4 sb = *(const uint4*)&yw32[(size_t)c * 64 + sub * 4];
    float4 cb0 = *(const float4*)&conv_bias[sub * 8];
    float4 cb1 = *(const float4*)&conv_bias[sub * 8 + 4];
    float4 lw0 = *(const float4*)&lin_w[sub * 8];
    float4 lw1 = *(const float4*)&lin_w[sub * 8 + 4];
    float h0 = fmaxf(dc * (a0 + bflo(sb.x)) + cb0.x, 0.f);
    float h1 = fmaxf(dc * (a1 + bfhi(sb.x)) + cb0.y, 0.f);
    float h2 = fmaxf(dc * (a2 + bflo(sb.y)) + cb0.z, 0.f);
    float h3 = fmaxf(dc * (a3 + bfhi(sb.y)) + cb0.w, 0.f);
    float h4 = fmaxf(dc * (a4 + bflo(sb.z)) + cb1.x, 0.f);
    float h5 = fmaxf(dc * (a5 + bfhi(sb.z)) + cb1.y, 0.f);
    float h6 = fmaxf(dc * (a6 + bflo(sb.w)) + cb1.z, 0.f);
    float h7 = fmaxf(dc * (a7 + bfhi(sb.w)) + cb1.w, 0.f);
    float part = (h0 * lw0.x + h1 * lw0.y + h2 * lw0.z + h3 * lw0.w)
               + (h4 * lw1.x + h5 * lw1.y + h6 * lw1.z + h7 * lw1.w);
    part = (q == 0) ? part : 0.f;
    part = wave_reduce(part);
    if (lane == 0) out[c] = part + lin_b[0];
}

// ---------------- launch ----------------

extern "C" void kernel_launch(void* const* d_in, const int* in_sizes, int n_in,
                              void* d_out, int out_size, void* d_ws, size_t ws_size,
                              hipStream_t stream) {
    const float* x         = (const float*)d_in[0];
    const int*   ei        = (const int*)  d_in[1];
    const float* W         = (const float*)d_in[2];
    const float* p         = (const float*)d_in[3];
    const float* w_ih      = (const float*)d_in[4];
    const float* w_hh      = (const float*)d_in[5];
    const float* b_ih      = (const float*)d_in[6];
    const float* b_hh      = (const float*)d_in[7];
    const float* conv_bias = (const float*)d_in[8];
    const float* lin_w     = (const float*)d_in[9];
    const float* lin_b     = (const float*)d_in[10];
    float* out = (float*)d_out;

    u32*   w  = (u32*)d_ws;
    float* wf = (float*)d_ws;

    // ws layout (word offsets), ~41.6 MB. G overlays PAIRS (dead before k_part).
    const size_t SCORES_W = 0;          // 100000
    const size_t DINV_W   = 100096;     // 100000
    const size_t OFFS_W   = 200192;     // 100001
    const size_t HIST16_W = 300288;     // 65536
    const size_t STATE_W  = 365824;     // 8 (unused, kept in memset range)
    const size_t GCUR_W   = 365832;     // 196 (memset covers hist16..gcur)
    const size_t TOPI_W   = 368128;     // 128
    const size_t GATE_W   = 368256;     // 128
    const size_t BFRAG_W  = 384768;     // 8192
    const size_t PAIRS_W  = 392960;     // 196 * 10240 = 2007040
    const size_t EBUF_W   = 2400000;    // 1600000
    const size_t YW_W     = 4000000;    // bf16 yw: 6400000 words

    float* scores  = wf + SCORES_W;
    float* dinv    = wf + DINV_W;
    u32*   offs    = w  + OFFS_W;
    u32*   hist16  = w  + HIST16_W;
    u32*   gcur    = w  + GCUR_W;
    u32*   top_idx = w  + TOPI_W;
    float* gate    = wf + GATE_W;
    u16*   Bfrag   = (u16*)(w + BFRAG_W);
    u32*   pairs   = w  + PAIRS_W;
    float* G       = wf + PAIRS_W;      // overlay (dead before k_part)
    u32*   ebuf    = w  + EBUF_W;
    u16*   yw      = (u16*)(w + YW_W);
    u32*   yw32    = w + YW_W;

    hipMemsetAsync(hist16, 0, (65536 + 8 + NBUCK) * sizeof(u32), stream);

    // --- top-k: scores+hist, then fused single-block select
    k_scores<<<25000, 256, 0, stream>>>(x, p, scores, hist16);
    k_topsel<<<1, 1024, 0, stream>>>(scores, p, hist16, top_idx, gate);

    // --- GRU -> W_new (bf16 fragment-packed)
    k_ggemm<<<dim3(4, 12), 256, 0, stream>>>(x, W, w_ih, w_hh, top_idx, gate, G);
    k_gate<<<64, 256, 0, stream>>>(G, W, b_ih, b_hh, Bfrag);

    // --- CSR build (fixed-capacity radix) -> offs, dinv, ebuf
    k_part<<<(N_EDGES + PB_EDGES - 1) / PB_EDGES, 256, 0, stream>>>(ei, gcur, pairs);
    k_csr<<<NBUCK, 256, 0, stream>>>(pairs, gcur, offs, dinv, ebuf);

    // --- yw = dinv * (x @ W_new)  (bf16 MFMA)
    k_gemm<<<1563, 256, 0, stream>>>(x, Bfrag, dinv, yw);

    // --- gather + fused head (two half-range dispatches for profile visibility)
    k_gather<<<12500, 256, 0, stream>>>(yw32, offs, ebuf, dinv, conv_bias, lin_w,
                                        lin_b, out, 0, 50000);
    k_gather<<<12500, 256, 0, stream>>>(yw32, offs, ebuf, dinv, conv_bias, lin_w,
                                        lin_b, out, 50000, N_NODES);
}